// Round 1
// baseline (2926.328 us; speedup 1.0000x reference)
//
#include <hip/hip_runtime.h>
#include <stdint.h>

#define V_ITEMS 100000
#define EDIM    128
#define BATCH   4096
#define HLEN    50
#define TOPK    21
#define NKEEP   32      // candidate superset per batch (margin over 21)
#define BTILE   16      // batches per block in scoring kernel
#define TPB     512     // threads per block (8 waves)
#define CAP     416     // candidate buffer capacity per batch
#define TRIG    128     // compact when cnt exceeds this
#define IPT     4       // items per thread per iteration
#define ITERSTEP (TPB*IPT)   // 2048 items per block-iteration

// ---------------- key packing: max(key) == max(val), tie -> min(idx) --------
__device__ inline uint64_t packkey(float v, unsigned idx) {
    unsigned u = __float_as_uint(v);
    u = (u & 0x80000000u) ? ~u : (u | 0x80000000u);   // orderable float
    return ((uint64_t)u << 32) | (uint64_t)(0xFFFFFFFFu - idx);
}
__device__ inline float unpackval(uint64_t k) {
    unsigned uv = (unsigned)(k >> 32);
    uv = (uv & 0x80000000u) ? (uv ^ 0x80000000u) : ~uv;
    return __uint_as_float(uv);
}
__device__ inline uint64_t wred_max(uint64_t k) {
    #pragma unroll
    for (int off = 32; off; off >>= 1) {
        uint64_t o = (uint64_t)__shfl_xor((unsigned long long)k, off);
        if (o > k) k = o;
    }
    return k;
}

// wave-cooperative top-NKEEP over vals[0..n) (index = idxs[i] or slot i).
// lane r (r<NKEEP) gets winner r in (*winv,*wini); *thr32 (all lanes) = 32nd val.
// Destructive: marks selected slots' vals to -inf.
template<bool HASIDX>
__device__ inline void wave_topk(float* vals, const int* idxs, int n, int lane,
                                 float* winv, int* wini, float* thr32) {
    float myv = -INFINITY; int myi = -1; float t = -INFINITY;
    for (int r = 0; r < NKEEP; r++) {
        uint64_t best = 0;
        for (int i = lane; i < n; i += 64) {
            int id = HASIDX ? idxs[i] : i;
            uint64_t k = packkey(vals[i], (unsigned)id);
            if (k > best) best = k;
        }
        best = wred_max(best);
        unsigned widx = 0xFFFFFFFFu - (unsigned)(best & 0xFFFFFFFFull);
        for (int i = lane; i < n; i += 64) {          // remove winner
            int id = HASIDX ? idxs[i] : i;
            if ((unsigned)id == widx) vals[i] = -INFINITY;
        }
        if (lane == r) { myv = unpackval(best); myi = (int)widx; }
        if (r == NKEEP - 1) t = unpackval(best);
    }
    *winv = myv; *wini = myi; *thr32 = t;
}

// ---------------- K1: masked mean-pool queries (fp32) -----------------------
__global__ __launch_bounds__(EDIM) void query_kernel(
        const int* __restrict__ seq, const int* __restrict__ len,
        const float* __restrict__ emb, float* __restrict__ qout) {
    int b = blockIdx.x, d = threadIdx.x;
    int n = len[b];
    float s = 0.f;
    for (int l = 0; l < n; l++) {
        int it = seq[b * HLEN + l];
        s += emb[(size_t)it * EDIM + d];
    }
    float denom = (float)(n > 0 ? n : 1);
    qout[(size_t)b * EDIM + d] = s / denom;
}

// ---------------- K2: fp32 scoring sweep + fused top-32 selection -----------
__global__ __launch_bounds__(TPB) void score_topk(
        const float* __restrict__ q, const float* __restrict__ emb,
        int* __restrict__ candOut) {
    __shared__ __align__(16) float qs[BTILE * EDIM];       // 8 KB
    __shared__ __align__(16) float cbuf[BTILE * CAP * 2];  // 53 KB: cv | ci
    __shared__ int   cnt[BTILE];
    __shared__ float thr[BTILE];
    float* cv  = cbuf;
    int*   ci  = (int*)(cbuf + BTILE * CAP);
    float* raw = cbuf;                                     // iter0 overlay

    const int tid  = threadIdx.x;
    const int lane = tid & 63;
    const int w    = tid >> 6;          // wave id 0..7; wave owns batches w, w+8
    const int b0   = blockIdx.x * BTILE;

    for (int i = tid; i < BTILE * EDIM; i += TPB) qs[i] = q[(size_t)b0 * EDIM + i];
    __syncthreads();
    const float4* qs4 = (const float4*)qs;

    // ---- iter0: items [0,TPB): raw scores to LDS, then per-wave top-32 ----
    {
        const float4* er = (const float4*)(emb + (size_t)tid * EDIM);
        float acc[BTILE];
        #pragma unroll
        for (int b = 0; b < BTILE; b++) acc[b] = 0.f;
        #pragma unroll 4
        for (int d4 = 0; d4 < EDIM / 4; d4++) {
            float4 e = er[d4];
            #pragma unroll
            for (int b = 0; b < BTILE; b++) {
                float4 qv = qs4[b * (EDIM / 4) + d4];
                acc[b] += e.x * qv.x + e.y * qv.y + e.z * qv.z + e.w * qv.w;
            }
        }
        #pragma unroll
        for (int b = 0; b < BTILE; b++) raw[b * TPB + tid] = acc[b];
    }
    __syncthreads();
    float wv[2]; int wi[2]; float t32[2];
    for (int p = 0; p < 2; p++) {
        int b = w + p * 8;
        wave_topk<false>(raw + b * TPB, nullptr, TPB, lane, &wv[p], &wi[p], &t32[p]);
    }
    __syncthreads();   // done reading raw (it overlays cv/ci)
    for (int p = 0; p < 2; p++) {
        int b = w + p * 8;
        if (lane < NKEEP) { cv[b * CAP + lane] = wv[p]; ci[b * CAP + lane] = wi[p]; }
        if (lane == 0)    { cnt[b] = NKEEP; thr[b] = t32[p]; }
    }

    // ---- main sweep: items [TPB, V), IPT per thread per iteration ----
    for (int base = TPB; base < V_ITEMS; base += ITERSTEP) {
        __syncthreads();                  // publish thr/cnt from prev compaction
        float tr[BTILE];
        #pragma unroll
        for (int b = 0; b < BTILE; b++) tr[b] = thr[b];

        int it[IPT]; const float4* er[IPT];
        #pragma unroll
        for (int k = 0; k < IPT; k++) {
            it[k] = base + tid + k * TPB;
            int cl = it[k] < V_ITEMS ? it[k] : (V_ITEMS - 1);
            er[k] = (const float4*)(emb + (size_t)cl * EDIM);
        }
        float acc[IPT][BTILE];
        #pragma unroll
        for (int k = 0; k < IPT; k++)
            #pragma unroll
            for (int b = 0; b < BTILE; b++) acc[k][b] = 0.f;

        #pragma unroll 4
        for (int d4 = 0; d4 < EDIM / 4; d4++) {
            float4 e[IPT];
            #pragma unroll
            for (int k = 0; k < IPT; k++) e[k] = er[k][d4];
            #pragma unroll
            for (int b = 0; b < BTILE; b++) {
                float4 qv = qs4[b * (EDIM / 4) + d4];   // wave-uniform broadcast
                #pragma unroll
                for (int k = 0; k < IPT; k++)
                    acc[k][b] += e[k].x * qv.x + e[k].y * qv.y
                               + e[k].z * qv.z + e[k].w * qv.w;
            }
        }
        #pragma unroll
        for (int k = 0; k < IPT; k++) {
            if (it[k] < V_ITEMS) {
                #pragma unroll
                for (int b = 0; b < BTILE; b++) {
                    float s = acc[k][b];
                    if (s > tr[b]) {
                        int pz = atomicAdd(&cnt[b], 1);
                        if (pz < CAP) { cv[b * CAP + pz] = s; ci[b * CAP + pz] = it[k]; }
                    }
                }
            }
        }
        __syncthreads();                  // inserts visible
        for (int p = 0; p < 2; p++) {     // per-wave compaction of owned batches
            int b = w + p * 8;
            int c = min(cnt[b], CAP);
            if (c > TRIG) {
                float cwv; int cwi; float ct;
                wave_topk<true>(cv + b * CAP, ci + b * CAP, c, lane, &cwv, &cwi, &ct);
                if (lane < NKEEP) { cv[b * CAP + lane] = cwv; ci[b * CAP + lane] = cwi; }
                if (lane == 0)    { cnt[b] = NKEEP; thr[b] = ct; }
            }
        }
    }

    // ---- final: top-32 per batch -> candidate indices to workspace ----
    __syncthreads();
    for (int p = 0; p < 2; p++) {
        int b = w + p * 8;
        int c = min(cnt[b], CAP);
        float fwv; int fwi; float ft;
        wave_topk<true>(cv + b * CAP, ci + b * CAP, c, lane, &fwv, &fwi, &ft);
        if (lane < NKEEP) candOut[(size_t)(b0 + b) * NKEEP + lane] = fwi;
    }
}

// ---------------- K3: fp64 rescore of 32 candidates, emit exact top-21 ------
__global__ __launch_bounds__(64) void rescore(
        const int* __restrict__ seq, const int* __restrict__ len,
        const float* __restrict__ emb, const int* __restrict__ cand,
        float* __restrict__ out) {
    __shared__ double qd[EDIM];
    int b = blockIdx.x, lane = threadIdx.x;
    int n = len[b];
    double s0 = 0.0, s1 = 0.0;
    for (int l = 0; l < n; l++) {
        int itv = seq[b * HLEN + l];
        const float* e = emb + (size_t)itv * EDIM;
        s0 += (double)e[lane];
        s1 += (double)e[lane + 64];
    }
    double denom = (double)(n > 0 ? n : 1);
    qd[lane]      = s0 / denom;
    qd[lane + 64] = s1 / denom;
    __syncthreads();

    int c    = lane & 31;
    int half = lane >> 5;
    int idx  = cand[(size_t)b * NKEEP + c];
    const float* ev = emb + (size_t)idx * EDIM;
    double part = 0.0;
    int off = half * 64;
    for (int j = 0; j < 64; j++) part += qd[off + j] * (double)ev[off + j];
    part += __shfl_xor(part, 32);       // combine the two halves
    double val = part;

    if (lane < 32) {
        int rank = 0;
        for (int j = 0; j < 32; j++) {
            double vj = __shfl(val, j);
            int    ij = __shfl(idx, j);
            if (vj > val || (vj == val && ij < idx)) rank++;
        }
        if (rank < TOPK) {
            out[(size_t)b * TOPK + rank] = (float)val;                       // values
            out[(size_t)BATCH * TOPK + (size_t)b * TOPK + rank] = (float)idx; // indices
        }
    }
}

extern "C" void kernel_launch(void* const* d_in, const int* in_sizes, int n_in,
                              void* d_out, int out_size, void* d_ws, size_t ws_size,
                              hipStream_t stream) {
    const int*   seq = (const int*)d_in[0];
    const int*   len = (const int*)d_in[1];
    const float* emb = (const float*)d_in[2];
    float* out = (float*)d_out;

    float* qws  = (float*)d_ws;                                        // 2 MB
    int*   cand = (int*)((char*)d_ws + (size_t)BATCH * EDIM * sizeof(float)); // 512 KB

    query_kernel<<<BATCH, EDIM, 0, stream>>>(seq, len, emb, qws);
    score_topk<<<BATCH / BTILE, TPB, 0, stream>>>(qws, emb, cand);
    rescore<<<BATCH, 64, 0, stream>>>(seq, len, emb, cand, out);
}